// Round 9
// baseline (712.121 us; speedup 1.0000x reference)
//
#include <hip/hip_runtime.h>
#include <hip/hip_bf16.h>
#include <math.h>

#define DIM_IN  2048
#define DIM_CTX 512
#define DIM_KEY 128
#define DIM_VAL 128
#define NCLIP   8
#define S_TOT   16384   // 16*32*32
#define NBOX    512
#define MAXB    96      // per-clip box capacity per pass (bp-loop handles overflow)

typedef __attribute__((ext_vector_type(8))) short short8_t;  // 8 bf16 = 4 VGPR
typedef __attribute__((ext_vector_type(4))) float f32x4;

__device__ inline unsigned short f2bf(float x) {            // RNE f32 -> bf16
    union { float f; unsigned int u; } v; v.f = x;
    unsigned int r = v.u + 0x7FFFu + ((v.u >> 16) & 1u);
    return (unsigned short)(r >> 16);
}
__device__ inline float bf2f(unsigned short h) {
    union { unsigned int u; float f; } v; v.u = ((unsigned int)h) << 16;
    return v.f;
}

// ---------------------------------------------------------------------------
// K0: per-clip box ranges [start,end) from sorted batch_idx; zero cctx.
// ---------------------------------------------------------------------------
__global__ __launch_bounds__(256) void k0_init(const int* __restrict__ batch_idx,
                                               int* __restrict__ ranges,
                                               float* __restrict__ cctx) {
    int idx = blockIdx.x * blockDim.x + threadIdx.x;
    for (int i = idx; i < NBOX * DIM_CTX; i += gridDim.x * blockDim.x)
        cctx[i] = 0.0f;
    if (blockIdx.x == 0) {
        __shared__ int s_start[NCLIP], s_end[NCLIP];
        if (threadIdx.x < NCLIP) { s_start[threadIdx.x] = NBOX; s_end[threadIdx.x] = 0; }
        __syncthreads();
        for (int i = threadIdx.x; i < NBOX; i += blockDim.x) {
            int b = batch_idx[i];
            atomicMin(&s_start[b], i);
            atomicMax(&s_end[b], i + 1);
        }
        __syncthreads();
        if (threadIdx.x < NCLIP) {
            ranges[threadIdx.x]         = s_start[threadIdx.x];
            ranges[NCLIP + threadIdx.x] = s_end[threadIdx.x];
        }
    }
}

// ---------------------------------------------------------------------------
// K1a: q = rois @ W_proj^T + b_proj   [NBOX, DIM_KEY]; 2 boxes/block, 256 blk
// ---------------------------------------------------------------------------
__global__ __launch_bounds__(128) void k1a_q(const float* __restrict__ rois,
                                             const float* __restrict__ W_proj,
                                             const float* __restrict__ b_proj,
                                             float* __restrict__ q) {
    __shared__ float s_roi[2 * DIM_IN];          // 16 KB
    int b0 = blockIdx.x * 2;
    const float4* src = (const float4*)(rois + (size_t)b0 * DIM_IN);
    for (int i = threadIdx.x; i < 2 * DIM_IN / 4; i += blockDim.x)
        ((float4*)s_roi)[i] = src[i];
    __syncthreads();
    int k = threadIdx.x;
    const float4* wrow = (const float4*)(W_proj + (size_t)k * DIM_IN);
    float a0 = 0.f, a1 = 0.f;
    for (int i = 0; i < DIM_IN / 4; ++i) {
        float4 w  = wrow[i];
        float4 r0 = *(const float4*)&s_roi[0 * DIM_IN + i * 4];
        float4 r1 = *(const float4*)&s_roi[1 * DIM_IN + i * 4];
        a0 += w.x * r0.x; a0 += w.y * r0.y; a0 += w.z * r0.z; a0 += w.w * r0.w;
        a1 += w.x * r1.x; a1 += w.y * r1.y; a1 += w.z * r1.z; a1 += w.w * r1.w;
    }
    float bp = b_proj[k];
    q[(size_t)(b0 + 0) * DIM_KEY + k] = a0 + bp;
    q[(size_t)(b0 + 1) * DIM_KEY + k] = a1 + bp;
}

// ---------------------------------------------------------------------------
// K1b: qW = q @ W_keys -> split bf16 (hi + residual lo); qbias = q . b_keys
// ---------------------------------------------------------------------------
__global__ __launch_bounds__(256) void k1b_qw(const float* __restrict__ q,
                                              const float* __restrict__ W_keys,
                                              const float* __restrict__ b_keys,
                                              unsigned short* __restrict__ qW_hi,
                                              unsigned short* __restrict__ qW_lo,
                                              float* __restrict__ qbias) {
    __shared__ float s_q[4 * DIM_KEY];
    __shared__ float red[256];
    int b0 = blockIdx.x * 4;
    for (int i = threadIdx.x; i < 4 * DIM_KEY; i += blockDim.x)
        s_q[i] = q[(size_t)b0 * DIM_KEY + i];
    __syncthreads();
    int c0 = threadIdx.x, c1 = threadIdx.x + 256;
    float a[4][2] = {{0.f,0.f},{0.f,0.f},{0.f,0.f},{0.f,0.f}};
    for (int k = 0; k < DIM_KEY; ++k) {
        float w0 = W_keys[(size_t)k * DIM_CTX + c0];
        float w1 = W_keys[(size_t)k * DIM_CTX + c1];
        float q0 = s_q[0 * DIM_KEY + k], q1 = s_q[1 * DIM_KEY + k];
        float q2 = s_q[2 * DIM_KEY + k], q3 = s_q[3 * DIM_KEY + k];
        a[0][0] += q0 * w0; a[0][1] += q0 * w1;
        a[1][0] += q1 * w0; a[1][1] += q1 * w1;
        a[2][0] += q2 * w0; a[2][1] += q2 * w1;
        a[3][0] += q3 * w0; a[3][1] += q3 * w1;
    }
    #pragma unroll
    for (int j = 0; j < 4; ++j) {
        #pragma unroll
        for (int cc = 0; cc < 2; ++cc) {
            int c = (cc == 0) ? c0 : c1;
            float x = a[j][cc];
            unsigned short h = f2bf(x);
            qW_hi[(size_t)(b0 + j) * DIM_CTX + c] = h;
            qW_lo[(size_t)(b0 + j) * DIM_CTX + c] = f2bf(x - bf2f(h));
        }
    }
    for (int j = 0; j < 4; ++j) {
        float v = 0.f;
        if (threadIdx.x < DIM_KEY) v = s_q[j * DIM_KEY + threadIdx.x] * b_keys[threadIdx.x];
        red[threadIdx.x] = v;
        __syncthreads();
        for (int st = 128; st > 0; st >>= 1) {
            if (threadIdx.x < st) red[threadIdx.x] += red[threadIdx.x + st];
            __syncthreads();
        }
        if (threadIdx.x == 0) qbias[b0 + j] = red[0];
        __syncthreads();
    }
}

// ---------------------------------------------------------------------------
// K2 (fused conv + scores + softmax partials):
//   reads fp32 ctx ONCE, writes ctxB bf16 (side output for K4),
//   in-LDS transpose -> bf16 B-fragments, MFMA scores (qW hi/lo split),
//   writes raw scores + per-(box,chunk) online-softmax partials.
// grid (128 s-chunks of 128, 8 clips); 256 threads; LDS 76 KB -> 2 blk/CU.
// ---------------------------------------------------------------------------
__global__ __launch_bounds__(256) void k2_scores(
    const float* __restrict__ ctx, unsigned short* __restrict__ ctxB,
    const unsigned short* __restrict__ qW_hi, const unsigned short* __restrict__ qW_lo,
    const float* __restrict__ qbias, const int* __restrict__ ranges,
    float* __restrict__ scores, float* __restrict__ pmax, float* __restrict__ psum)
{
    int n = blockIdx.y;
    int start = ranges[n], Mb = ranges[NCLIP + n] - start;
    if (Mb <= 0) return;
    const float* ctxn = ctx + (size_t)n * DIM_CTX * S_TOT;
    unsigned short* ctxBn = ctxB + (size_t)n * DIM_CTX * S_TOT;
    int sch = blockIdx.x * 128;
    int t = threadIdx.x, lane = t & 63, w = t >> 6;

    __shared__ float          ls_f[64 * 132];     // 33792 B fp32 stage (pad 132)
    __shared__ unsigned short ls_b[128 * 64];     // 16384 B [s][c] swz (bf16)
    __shared__ unsigned short ls_qh[MAXB * 64];   // 12288 B
    __shared__ unsigned short ls_ql[MAXB * 64];   // 12288 B
    __shared__ float          red_mx[4][MAXB];    //  1536 B
    __shared__ float          red_sm[4][MAXB];    //  1536 B   total 77824 B

    for (int bp = 0; bp < Mb; bp += MAXB) {
        int nb = min(MAXB, Mb - bp);
        f32x4 acc[6][2];
        #pragma unroll
        for (int m = 0; m < 6; ++m)
            #pragma unroll
            for (int nn = 0; nn < 2; ++nn)
                acc[m][nn] = (f32x4){0.f, 0.f, 0.f, 0.f};

        for (int it = 0; it < 8; ++it) {
            int c0 = it * 64;
            __syncthreads();   // previous phase's LDS readers done
            // --- phase A: fp32 ctx tile [64 c][128 s] -> LDS; bf16 -> ctxB
            #pragma unroll
            for (int rep = 0; rep < 8; ++rep) {
                int idx = t + rep * 256;
                int c_l = idx >> 5, s4 = (idx & 31) * 4;
                float4 v = *(const float4*)(ctxn + (size_t)(c0 + c_l) * S_TOT + sch + s4);
                *(float4*)&ls_f[c_l * 132 + s4] = v;
                if (bp == 0) {
                    uint2 pk;
                    pk.x = f2bf(v.x) | ((unsigned)f2bf(v.y) << 16);
                    pk.y = f2bf(v.z) | ((unsigned)f2bf(v.w) << 16);
                    *(uint2*)(ctxBn + (size_t)(c0 + c_l) * S_TOT + sch + s4) = pk;
                }
            }
            // --- stage qW chunk hi/lo [96][64] (swizzled rows)
            for (int idx = t; idx < MAXB * 8; idx += 256) {
                int row = idx >> 3, c8 = (idx & 7) * 8;
                uint4 vh = {0,0,0,0}, vl = {0,0,0,0};
                if (row < nb) {
                    size_t go = (size_t)(start + bp + row) * DIM_CTX + c0 + c8;
                    vh = *(const uint4*)(qW_hi + go);
                    vl = *(const uint4*)(qW_lo + go);
                }
                int off = (row * 128 + c8 * 2) ^ ((row & 7) << 4);
                *(uint4*)((char*)ls_qh + off) = vh;
                *(uint4*)((char*)ls_ql + off) = vl;
            }
            __syncthreads();
            // --- phase B: transpose ls_f -> ls_b bf16 [128 s][64 c] swz
            {
                int s_l = t >> 1, ch = (t & 1) * 32;
                unsigned int pk[16];
                #pragma unroll
                for (int i = 0; i < 16; ++i) {
                    unsigned short h0 = f2bf(ls_f[(ch + 2 * i + 0) * 132 + s_l]);
                    unsigned short h1 = f2bf(ls_f[(ch + 2 * i + 1) * 132 + s_l]);
                    pk[i] = h0 | ((unsigned)h1 << 16);
                }
                int sw = (s_l & 7) << 4;
                int base = s_l * 128 + ch * 2;
                #pragma unroll
                for (int i = 0; i < 4; ++i)
                    *(uint4*)((char*)ls_b + ((base + i * 16) ^ sw)) = *(uint4*)&pk[i * 4];
            }
            __syncthreads();
            // --- phase C: 2 k-steps of K=32; skip m-tiles >= nb
            #pragma unroll
            for (int ks = 0; ks < 2; ++ks) {
                int hi16 = ks * 64 + (lane >> 4) * 16;
                short8_t Ah[6], Al[6], Bv[2];
                #pragma unroll
                for (int m = 0; m < 6; ++m) {
                    if (m * 16 < nb) {
                        int row = m * 16 + (lane & 15);
                        int off = (row * 128 + hi16) ^ ((row & 7) << 4);
                        Ah[m] = *(const short8_t*)((const char*)ls_qh + off);
                        Al[m] = *(const short8_t*)((const char*)ls_ql + off);
                    }
                }
                #pragma unroll
                for (int nn = 0; nn < 2; ++nn) {
                    int srow = (w * 2 + nn) * 16 + (lane & 15);
                    int off = (srow * 128 + hi16) ^ ((srow & 7) << 4);
                    Bv[nn] = *(const short8_t*)((const char*)ls_b + off);
                }
                #pragma unroll
                for (int m = 0; m < 6; ++m) {
                    if (m * 16 < nb) {
                        #pragma unroll
                        for (int nn = 0; nn < 2; ++nn) {
                            acc[m][nn] = __builtin_amdgcn_mfma_f32_16x16x32_bf16(Ah[m], Bv[nn], acc[m][nn], 0, 0, 0);
                            acc[m][nn] = __builtin_amdgcn_mfma_f32_16x16x32_bf16(Al[m], Bv[nn], acc[m][nn], 0, 0, 0);
                        }
                    }
                }
            }
        }
        // --- epilogue: scores + per-(box,chunk) softmax partials
        const float rs = 0.08838834764831845f;  // 1/sqrt(128)
        #pragma unroll
        for (int m = 0; m < 6; ++m) {
            if (m * 16 >= nb) continue;          // wave-uniform skip
            #pragma unroll
            for (int r = 0; r < 4; ++r) {
                int b_l = m * 16 + ((lane >> 4) << 2) + r;   // uniform per 16-lane group
                bool valid = b_l < nb;
                int bg = start + bp + b_l;
                float sc0, sc1;
                if (valid) {
                    float qb = qbias[bg];
                    sc0 = (acc[m][0][r] + qb) * rs;
                    sc1 = (acc[m][1][r] + qb) * rs;
                    int s0 = sch + (w * 2 + 0) * 16 + (lane & 15);
                    scores[(size_t)bg * S_TOT + s0]      = sc0;
                    scores[(size_t)bg * S_TOT + s0 + 16] = sc1;
                } else {
                    sc0 = sc1 = -1e30f;
                }
                float mx = fmaxf(sc0, sc1);
                #pragma unroll
                for (int d = 1; d < 16; d <<= 1) mx = fmaxf(mx, __shfl_xor(mx, d, 16));
                float e = __expf(sc0 - mx) + __expf(sc1 - mx);
                #pragma unroll
                for (int d = 1; d < 16; d <<= 1) e += __shfl_xor(e, d, 16);
                if ((lane & 15) == 0) { red_mx[w][b_l] = mx; red_sm[w][b_l] = e; }
            }
        }
        __syncthreads();
        if (t < MAXB && t < nb) {
            float m0 = red_mx[0][t], m1 = red_mx[1][t], m2 = red_mx[2][t], m3 = red_mx[3][t];
            float M = fmaxf(fmaxf(m0, m1), fmaxf(m2, m3));
            float S = red_sm[0][t] * __expf(m0 - M) + red_sm[1][t] * __expf(m1 - M)
                    + red_sm[2][t] * __expf(m2 - M) + red_sm[3][t] * __expf(m3 - M);
            int bg = start + bp + t;
            pmax[(size_t)bg * 128 + blockIdx.x] = M;
            psum[(size_t)bg * 128 + blockIdx.x] = S;
        }
        __syncthreads();  // protect LDS before next bp pass
    }
}

// ---------------------------------------------------------------------------
// K3r: reduce per-chunk partials -> rmax, rsum (1/sum-exp). 512 blk x 128 thr.
// ---------------------------------------------------------------------------
__global__ __launch_bounds__(128) void k3r(const float* __restrict__ pmax,
                                           const float* __restrict__ psum,
                                           float* __restrict__ rmax,
                                           float* __restrict__ rsum) {
    int b = blockIdx.x, t = threadIdx.x;
    float m = pmax[(size_t)b * 128 + t];
    float s = psum[(size_t)b * 128 + t];
    __shared__ float sm[2], ss[2];
    float M = m;
    #pragma unroll
    for (int d = 1; d < 64; d <<= 1) M = fmaxf(M, __shfl_xor(M, d, 64));
    if ((t & 63) == 0) sm[t >> 6] = M;
    __syncthreads();
    float Mg = fmaxf(sm[0], sm[1]);
    float e = s * __expf(m - Mg);
    #pragma unroll
    for (int d = 1; d < 64; d <<= 1) e += __shfl_xor(e, d, 64);
    if ((t & 63) == 0) ss[t >> 6] = e;
    __syncthreads();
    if (t == 0) { rmax[b] = Mg; rsum[b] = 1.0f / (ss[0] + ss[1]); }
}

// ---------------------------------------------------------------------------
// K4: coeff = softmax(scores); attn = 255*coeff (in-place); cctx += coeff.ctx
// via bf16 MFMA. B = ctxB bf16 (direct uint4 copy). 64-c tiles (8 phases).
// Wave (mh,ns): m-tiles {mh,mh+2,mh+4}, c-subtiles {ns*2, ns*2+1}.
// f32 atomics to cctx. LDS 80 KB -> 2 blk/CU.
// ---------------------------------------------------------------------------
__global__ __launch_bounds__(256) void k4_pv(
    const unsigned short* __restrict__ ctxB, const int* __restrict__ ranges,
    const float* __restrict__ rmax, const float* __restrict__ rsum,
    float* __restrict__ attn, float* __restrict__ cctx)
{
    int n = blockIdx.y;
    int start = ranges[n], Mb = ranges[NCLIP + n] - start;
    if (Mb <= 0) return;
    const unsigned short* ctxn = ctxB + (size_t)n * DIM_CTX * S_TOT;
    int sch = blockIdx.x * 256;
    int t = threadIdx.x, lane = t & 63, w = t >> 6;
    int mh = w >> 1, ns = w & 1;

    __shared__ unsigned short ls_p[MAXB * 256];   // 49152 B  [96 b][256 s] swz
    __shared__ unsigned short ls_c[64 * 256];     // 32768 B  [64 c][256 s] swz

    for (int bp = 0; bp < Mb; bp += MAXB) {
        int nb = min(MAXB, Mb - bp);
        bool a0v = (mh + 0) * 16 < nb;
        bool a1v = (mh + 2) * 16 < nb;
        bool a2v = (mh + 4) * 16 < nb;
        __syncthreads();
        // stage p (bf16, swizzled); write attn = 255*p (fp32, exact)
        for (int idx = t; idx < MAXB * 64; idx += 256) {
            int b_l = idx >> 6, s4 = (idx & 63) * 4;
            uint2 pk; pk.x = 0u; pk.y = 0u;
            if (b_l < nb) {
                int bg = start + bp + b_l;
                size_t off = (size_t)bg * S_TOT + sch + s4;
                float4 v = *(const float4*)(attn + off);
                float m = rmax[bg], r = rsum[bg];
                float4 p;
                p.x = __expf(v.x - m) * r; p.y = __expf(v.y - m) * r;
                p.z = __expf(v.z - m) * r; p.w = __expf(v.w - m) * r;
                float4 o;
                o.x = 255.f * p.x; o.y = 255.f * p.y; o.z = 255.f * p.z; o.w = 255.f * p.w;
                *(float4*)(attn + off) = o;
                pk.x = f2bf(p.x) | ((unsigned)f2bf(p.y) << 16);
                pk.y = f2bf(p.z) | ((unsigned)f2bf(p.w) << 16);
            }
            int off8 = (b_l * 512 + s4 * 2) ^ ((b_l & 7) << 4);
            *(uint2*)((char*)ls_p + off8) = pk;
        }
        __syncthreads();
        // cache A-frags (p): wave's active m-tiles x 8 k-steps
        short8_t A[3][8];
        int hi16 = (lane >> 4) * 16;
        #pragma unroll
        for (int mi = 0; mi < 3; ++mi) {
            int tm = mh + 2 * mi;
            if (tm * 16 < nb) {
                int row = tm * 16 + (lane & 15);
                int sw = (row & 7) << 4;
                #pragma unroll
                for (int k = 0; k < 8; ++k) {
                    int off = (row * 512 + k * 64 + hi16) ^ sw;
                    A[mi][k] = *(const short8_t*)((const char*)ls_p + off);
                }
            }
        }
        // c-tile loop: stage ctxB [64 c][256 s] bf16 (direct copy), 8 k-steps
        for (int ct = 0; ct < 8; ++ct) {
            __syncthreads();
            #pragma unroll
            for (int r = 0; r < 8; ++r) {
                int idx = t + r * 256;
                int c_l = idx >> 5, s8 = (idx & 31) * 8;
                uint4 v = *(const uint4*)(ctxn + (size_t)(ct * 64 + c_l) * S_TOT + sch + s8);
                int off8 = (c_l * 512 + s8 * 2) ^ ((c_l & 7) << 4);
                *(uint4*)((char*)ls_c + off8) = v;
            }
            __syncthreads();
            f32x4 acc[3][2];
            #pragma unroll
            for (int mi = 0; mi < 3; ++mi)
                #pragma unroll
                for (int cn = 0; cn < 2; ++cn)
                    acc[mi][cn] = (f32x4){0,0,0,0};
            #pragma unroll
            for (int cn = 0; cn < 2; ++cn) {
                int crow = (ns * 2 + cn) * 16 + (lane & 15);
                int swc = (crow & 7) << 4;
                #pragma unroll
                for (int k = 0; k < 8; ++k) {
                    int off = (crow * 512 + k * 64 + hi16) ^ swc;
                    short8_t B = *(const short8_t*)((const char*)ls_c + off);
                    if (a0v) acc[0][cn] = __builtin_amdgcn_mfma_f32_16x16x32_bf16(A[0][k], B, acc[0][cn], 0, 0, 0);
                    if (a1v) acc[1][cn] = __builtin_amdgcn_mfma_f32_16x16x32_bf16(A[1][k], B, acc[1][cn], 0, 0, 0);
                    if (a2v) acc[2][cn] = __builtin_amdgcn_mfma_f32_16x16x32_bf16(A[2][k], B, acc[2][cn], 0, 0, 0);
                }
            }
            #pragma unroll
            for (int cn = 0; cn < 2; ++cn) {
                int cg = ct * 64 + (ns * 2 + cn) * 16 + (lane & 15);
                #pragma unroll
                for (int r = 0; r < 4; ++r) {
                    int br = ((lane >> 4) << 2) + r;
                    int b0l = (mh + 0) * 16 + br;
                    int b1l = (mh + 2) * 16 + br;
                    int b2l = (mh + 4) * 16 + br;
                    if (a0v && b0l < nb) atomicAdd(&cctx[(size_t)(start + bp + b0l) * DIM_CTX + cg], acc[0][cn][r]);
                    if (a1v && b1l < nb) atomicAdd(&cctx[(size_t)(start + bp + b1l) * DIM_CTX + cg], acc[1][cn][r]);
                    if (a2v && b2l < nb) atomicAdd(&cctx[(size_t)(start + bp + b2l) * DIM_CTX + cg], acc[2][cn][r]);
                }
            }
        }
    }
}

// ---------------------------------------------------------------------------
// K5: ctx_out[b,v] = cctx[b,:] . W_vals[v,:] + b_vals[v]
// ---------------------------------------------------------------------------
__global__ __launch_bounds__(128) void k5_out(const float* __restrict__ cctx,
                                              const float* __restrict__ W_vals,
                                              const float* __restrict__ b_vals,
                                              float* __restrict__ out) {
    __shared__ float s_c[4 * DIM_CTX];
    int b0 = blockIdx.x * 4;
    const float4* src = (const float4*)(cctx + (size_t)b0 * DIM_CTX);
    for (int i = threadIdx.x; i < 4 * DIM_CTX / 4; i += blockDim.x)
        ((float4*)s_c)[i] = src[i];
    __syncthreads();
    int v = threadIdx.x;
    const float4* wrow = (const float4*)(W_vals + (size_t)v * DIM_CTX);
    float a0 = 0.f, a1 = 0.f, a2 = 0.f, a3 = 0.f;
    for (int i = 0; i < DIM_CTX / 4; ++i) {
        float4 w  = wrow[i];
        float4 c0v = *(const float4*)&s_c[0 * DIM_CTX + i * 4];
        float4 c1v = *(const float4*)&s_c[1 * DIM_CTX + i * 4];
        float4 c2v = *(const float4*)&s_c[2 * DIM_CTX + i * 4];
        float4 c3v = *(const float4*)&s_c[3 * DIM_CTX + i * 4];
        a0 += w.x * c0v.x; a0 += w.y * c0v.y; a0 += w.z * c0v.z; a0 += w.w * c0v.w;
        a1 += w.x * c1v.x; a1 += w.y * c1v.y; a1 += w.z * c1v.z; a1 += w.w * c1v.w;
        a2 += w.x * c2v.x; a2 += w.y * c2v.y; a2 += w.z * c2v.z; a2 += w.w * c2v.w;
        a3 += w.x * c3v.x; a3 += w.y * c3v.y; a3 += w.z * c3v.z; a3 += w.w * c3v.w;
    }
    float bb = b_vals[v];
    out[(size_t)(b0 + 0) * DIM_VAL + v] = a0 + bb;
    out[(size_t)(b0 + 1) * DIM_VAL + v] = a1 + bb;
    out[(size_t)(b0 + 2) * DIM_VAL + v] = a2 + bb;
    out[(size_t)(b0 + 3) * DIM_VAL + v] = a3 + bb;
}

extern "C" void kernel_launch(void* const* d_in, const int* in_sizes, int n_in,
                              void* d_out, int out_size, void* d_ws, size_t ws_size,
                              hipStream_t stream) {
    const float* rois      = (const float*)d_in[0];
    const float* context   = (const float*)d_in[1];
    const int*   batch_idx = (const int*)  d_in[2];
    const float* W_proj    = (const float*)d_in[3];
    const float* b_proj    = (const float*)d_in[4];
    const float* W_keys    = (const float*)d_in[5];
    const float* b_keys    = (const float*)d_in[6];
    const float* W_vals    = (const float*)d_in[7];
    const float* b_vals    = (const float*)d_in[8];

    float* out  = (float*)d_out;                 // [NBOX, DIM_VAL]
    float* attn = out + NBOX * DIM_VAL;          // [NBOX, S_TOT] scores/attn

    // workspace layout (~132 MB of the 1 GiB ws)
    char* wsb = (char*)d_ws;
    int*   ranges = (int*)wsb;                                   // 128 B
    float* q      = (float*)(wsb + 128);                         // 512*128
    float* qbias  = q + NBOX * DIM_KEY;                          // 512
    float* rmaxp  = qbias + NBOX;                                // 512
    float* rsump  = rmaxp + NBOX;                                // 512
    float* cctx   = rsump + NBOX;                                // 512*512
    float* pmaxp  = cctx + NBOX * DIM_CTX;                       // 512*128
    float* psump  = pmaxp + NBOX * 128;                          // 512*128
    unsigned short* qW_hi = (unsigned short*)(psump + NBOX * 128);     // 512*512
    unsigned short* qW_lo = qW_hi + NBOX * DIM_CTX;                    // 512*512
    unsigned short* ctxB  = qW_lo + NBOX * DIM_CTX;              // 8*512*16384 bf16 (128 MiB)

    k0_init  <<<dim3(64),       dim3(256), 0, stream>>>(batch_idx, ranges, cctx);
    k1a_q    <<<dim3(NBOX / 2), dim3(128), 0, stream>>>(rois, W_proj, b_proj, q);
    k1b_qw   <<<dim3(NBOX / 4), dim3(256), 0, stream>>>(q, W_keys, b_keys, qW_hi, qW_lo, qbias);
    k2_scores<<<dim3(128, 8),   dim3(256), 0, stream>>>(context, ctxB, qW_hi, qW_lo, qbias, ranges, attn, pmaxp, psump);
    k3r      <<<dim3(NBOX),     dim3(128), 0, stream>>>(pmaxp, psump, rmaxp, rsump);
    k4_pv    <<<dim3(64, 8),    dim3(256), 0, stream>>>(ctxB, ranges, rmaxp, rsump, attn, cctx);
    k5_out   <<<dim3(NBOX / 4), dim3(128), 0, stream>>>(cctx, W_vals, b_vals, out);
}

// Round 11
// 634.404 us; speedup vs baseline: 1.1225x; 1.1225x over previous
//
#include <hip/hip_runtime.h>
#include <hip/hip_bf16.h>
#include <math.h>

#define DIM_IN  2048
#define DIM_CTX 512
#define DIM_KEY 128
#define DIM_VAL 128
#define NCLIP   8
#define S_TOT   16384   // 16*32*32
#define NBOX    512
#define MAXB    96      // per-clip box capacity per pass (bp-loop handles overflow)

typedef __attribute__((ext_vector_type(8))) short short8_t;  // 8 bf16 = 4 VGPR
typedef __attribute__((ext_vector_type(4))) float f32x4;

__device__ inline unsigned short f2bf(float x) {            // RNE f32 -> bf16
    union { float f; unsigned int u; } v; v.f = x;
    unsigned int r = v.u + 0x7FFFu + ((v.u >> 16) & 1u);
    return (unsigned short)(r >> 16);
}
__device__ inline float bf2f(unsigned short h) {
    union { unsigned int u; float f; } v; v.u = ((unsigned int)h) << 16;
    return v.f;
}

// ---------------------------------------------------------------------------
// K0: per-clip box ranges [start,end) from sorted batch_idx; zero cctx.
// ---------------------------------------------------------------------------
__global__ __launch_bounds__(256) void k0_init(const int* __restrict__ batch_idx,
                                               int* __restrict__ ranges,
                                               float* __restrict__ cctx) {
    int idx = blockIdx.x * blockDim.x + threadIdx.x;
    for (int i = idx; i < NBOX * DIM_CTX; i += gridDim.x * blockDim.x)
        cctx[i] = 0.0f;
    if (blockIdx.x == 0) {
        __shared__ int s_start[NCLIP], s_end[NCLIP];
        if (threadIdx.x < NCLIP) { s_start[threadIdx.x] = NBOX; s_end[threadIdx.x] = 0; }
        __syncthreads();
        for (int i = threadIdx.x; i < NBOX; i += blockDim.x) {
            int b = batch_idx[i];
            atomicMin(&s_start[b], i);
            atomicMax(&s_end[b], i + 1);
        }
        __syncthreads();
        if (threadIdx.x < NCLIP) {
            ranges[threadIdx.x]         = s_start[threadIdx.x];
            ranges[NCLIP + threadIdx.x] = s_end[threadIdx.x];
        }
    }
}

// ---------------------------------------------------------------------------
// K1a: q = rois @ W_proj^T + b_proj      [NBOX, DIM_KEY]
// ---------------------------------------------------------------------------
__global__ __launch_bounds__(128) void k1a_q(const float* __restrict__ rois,
                                             const float* __restrict__ W_proj,
                                             const float* __restrict__ b_proj,
                                             float* __restrict__ q) {
    __shared__ float s_roi[4 * DIM_IN];          // 32 KB
    int b0 = blockIdx.x * 4;
    const float4* src = (const float4*)(rois + (size_t)b0 * DIM_IN);
    for (int i = threadIdx.x; i < 4 * DIM_IN / 4; i += blockDim.x)
        ((float4*)s_roi)[i] = src[i];
    __syncthreads();
    int k = threadIdx.x;
    const float4* wrow = (const float4*)(W_proj + (size_t)k * DIM_IN);
    float a0 = 0.f, a1 = 0.f, a2 = 0.f, a3 = 0.f;
    for (int i = 0; i < DIM_IN / 4; ++i) {
        float4 w  = wrow[i];
        float4 r0 = *(const float4*)&s_roi[0 * DIM_IN + i * 4];
        float4 r1 = *(const float4*)&s_roi[1 * DIM_IN + i * 4];
        float4 r2 = *(const float4*)&s_roi[2 * DIM_IN + i * 4];
        float4 r3 = *(const float4*)&s_roi[3 * DIM_IN + i * 4];
        a0 += w.x * r0.x; a0 += w.y * r0.y; a0 += w.z * r0.z; a0 += w.w * r0.w;
        a1 += w.x * r1.x; a1 += w.y * r1.y; a1 += w.z * r1.z; a1 += w.w * r1.w;
        a2 += w.x * r2.x; a2 += w.y * r2.y; a2 += w.z * r2.z; a2 += w.w * r2.w;
        a3 += w.x * r3.x; a3 += w.y * r3.y; a3 += w.z * r3.z; a3 += w.w * r3.w;
    }
    float bp = b_proj[k];
    q[(size_t)(b0 + 0) * DIM_KEY + k] = a0 + bp;
    q[(size_t)(b0 + 1) * DIM_KEY + k] = a1 + bp;
    q[(size_t)(b0 + 2) * DIM_KEY + k] = a2 + bp;
    q[(size_t)(b0 + 3) * DIM_KEY + k] = a3 + bp;
}

// ---------------------------------------------------------------------------
// K1b: qW = q @ W_keys -> split bf16 (hi + residual lo); qbias = q . b_keys
// ---------------------------------------------------------------------------
__global__ __launch_bounds__(256) void k1b_qw(const float* __restrict__ q,
                                              const float* __restrict__ W_keys,
                                              const float* __restrict__ b_keys,
                                              unsigned short* __restrict__ qW_hi,
                                              unsigned short* __restrict__ qW_lo,
                                              float* __restrict__ qbias) {
    __shared__ float s_q[4 * DIM_KEY];
    __shared__ float red[256];
    int b0 = blockIdx.x * 4;
    for (int i = threadIdx.x; i < 4 * DIM_KEY; i += blockDim.x)
        s_q[i] = q[(size_t)b0 * DIM_KEY + i];
    __syncthreads();
    int c0 = threadIdx.x, c1 = threadIdx.x + 256;
    float a[4][2] = {{0.f,0.f},{0.f,0.f},{0.f,0.f},{0.f,0.f}};
    for (int k = 0; k < DIM_KEY; ++k) {
        float w0 = W_keys[(size_t)k * DIM_CTX + c0];
        float w1 = W_keys[(size_t)k * DIM_CTX + c1];
        float q0 = s_q[0 * DIM_KEY + k], q1 = s_q[1 * DIM_KEY + k];
        float q2 = s_q[2 * DIM_KEY + k], q3 = s_q[3 * DIM_KEY + k];
        a[0][0] += q0 * w0; a[0][1] += q0 * w1;
        a[1][0] += q1 * w0; a[1][1] += q1 * w1;
        a[2][0] += q2 * w0; a[2][1] += q2 * w1;
        a[3][0] += q3 * w0; a[3][1] += q3 * w1;
    }
    #pragma unroll
    for (int j = 0; j < 4; ++j) {
        #pragma unroll
        for (int cc = 0; cc < 2; ++cc) {
            int c = (cc == 0) ? c0 : c1;
            float x = a[j][cc];
            unsigned short h = f2bf(x);
            qW_hi[(size_t)(b0 + j) * DIM_CTX + c] = h;
            qW_lo[(size_t)(b0 + j) * DIM_CTX + c] = f2bf(x - bf2f(h));
        }
    }
    for (int j = 0; j < 4; ++j) {
        float v = 0.f;
        if (threadIdx.x < DIM_KEY) v = s_q[j * DIM_KEY + threadIdx.x] * b_keys[threadIdx.x];
        red[threadIdx.x] = v;
        __syncthreads();
        for (int st = 128; st > 0; st >>= 1) {
            if (threadIdx.x < st) red[threadIdx.x] += red[threadIdx.x + st];
            __syncthreads();
        }
        if (threadIdx.x == 0) qbias[b0 + j] = red[0];
        __syncthreads();
    }
}

// ---------------------------------------------------------------------------
// K2: scores[b,s] = (qW[b,:].ctx[n,:,s] + qbias[b]) / sqrt(dk)  via MFMA.
// qW split-bf16 (hi/lo); ctx single bf16 (lo dropped — validated 4.9e-4).
// Per block: s-chunk 128, all (<=96) boxes of clip; ctx read ONCE per clip.
// In-LDS transpose: fp32 stage [32c][128s] (pad 132, b128) -> bf16 ctxT
// [128s][32c] swz, SINGLE convert. 2 MFMAs/tile (Ah.B + Al.B).
// LDS 37376 B -> 4 blocks/CU (was 45568/3).
// ---------------------------------------------------------------------------
__global__ __launch_bounds__(256) void k2_scores(
    const float* __restrict__ ctx, const unsigned short* __restrict__ qW_hi,
    const unsigned short* __restrict__ qW_lo, const float* __restrict__ qbias,
    const int* __restrict__ ranges, float* __restrict__ scores)
{
    int n = blockIdx.y;
    int start = ranges[n], Mb = ranges[NCLIP + n] - start;
    if (Mb <= 0) return;
    const float* ctxn = ctx + (size_t)n * DIM_CTX * S_TOT;
    int sch = blockIdx.x * 128;
    int t = threadIdx.x, lane = t & 63, w = t >> 6;

    __shared__ float          ls_f[32 * 132];     // 16896 B (pad 132: b128-aligned)
    __shared__ unsigned short ls_qh[MAXB * 32];   //  6144 B
    __shared__ unsigned short ls_ql[MAXB * 32];   //  6144 B
    __shared__ unsigned short ls_th[128 * 32];    //  8192 B   (total 37376)

    for (int bp = 0; bp < Mb; bp += MAXB) {
        int nb = min(MAXB, Mb - bp);
        f32x4 acc[6][2];
        #pragma unroll
        for (int m = 0; m < 6; ++m)
            #pragma unroll
            for (int nn = 0; nn < 2; ++nn)
                acc[m][nn] = (f32x4){0.f, 0.f, 0.f, 0.f};

        for (int ch = 0; ch < 16; ++ch) {
            int c0 = ch * 32;
            __syncthreads();   // previous iteration's LDS readers done
            // --- stage fp32 ctx tile [32 c][128 s], padded rows of 132
            #pragma unroll
            for (int rep = 0; rep < 4; ++rep) {
                int idx = t + rep * 256;
                int c_l = idx >> 5, s4 = (idx & 31) * 4;
                float4 v = *(const float4*)(ctxn + (size_t)(c0 + c_l) * S_TOT + sch + s4);
                *(float4*)&ls_f[c_l * 132 + s4] = v;
            }
            // --- stage qW chunk hi/lo [96][32] (swizzled rows)
            for (int idx = t; idx < MAXB * 4; idx += 256) {
                int row = idx >> 2, c8 = (idx & 3) * 8;
                uint4 vh = {0,0,0,0}, vl = {0,0,0,0};
                if (row < nb) {
                    size_t go = (size_t)(start + bp + row) * DIM_CTX + c0 + c8;
                    vh = *(const uint4*)(qW_hi + go);
                    vl = *(const uint4*)(qW_lo + go);
                }
                int off = (row * 64 + c8 * 2) ^ ((row & 7) << 4);
                *(uint4*)((char*)ls_qh + off) = vh;
                *(uint4*)((char*)ls_ql + off) = vl;
            }
            __syncthreads();   // ls_f / ls_q ready
            // --- transpose+convert: ctxT [128 s][32 c] bf16 (single convert)
            {
                int s_l = t >> 1, c16 = (t & 1) * 16;
                unsigned short hb[16];
                #pragma unroll
                for (int i = 0; i < 16; ++i)
                    hb[i] = f2bf(ls_f[(c16 + i) * 132 + s_l]);
                int base = s_l * 64 + c16 * 2;
                int sw = (s_l & 7) << 4;
                uint4 p0, p1;
                p0.x = hb[0] | ((unsigned)hb[1] << 16);  p0.y = hb[2] | ((unsigned)hb[3] << 16);
                p0.z = hb[4] | ((unsigned)hb[5] << 16);  p0.w = hb[6] | ((unsigned)hb[7] << 16);
                p1.x = hb[8] | ((unsigned)hb[9] << 16);  p1.y = hb[10] | ((unsigned)hb[11] << 16);
                p1.z = hb[12] | ((unsigned)hb[13] << 16); p1.w = hb[14] | ((unsigned)hb[15] << 16);
                *(uint4*)((char*)ls_th + ((base)      ^ sw)) = p0;
                *(uint4*)((char*)ls_th + ((base + 16) ^ sw)) = p1;
            }
            __syncthreads();   // ctxT ready
            // --- one MFMA k-step (K=32 channels); skip m-tiles >= nb
            short8_t Ah[6], Al[6], Bh[2];
            int hi16 = (lane >> 4) * 16;
            #pragma unroll
            for (int m = 0; m < 6; ++m) {
                if (m * 16 < nb) {
                    int row = m * 16 + (lane & 15);
                    int off = (row * 64 + hi16) ^ ((row & 7) << 4);
                    Ah[m] = *(const short8_t*)((const char*)ls_qh + off);
                    Al[m] = *(const short8_t*)((const char*)ls_ql + off);
                }
            }
            #pragma unroll
            for (int nn = 0; nn < 2; ++nn) {
                int srow = (w * 2 + nn) * 16 + (lane & 15);
                int off = (srow * 64 + hi16) ^ ((srow & 7) << 4);
                Bh[nn] = *(const short8_t*)((const char*)ls_th + off);
            }
            #pragma unroll
            for (int m = 0; m < 6; ++m) {
                if (m * 16 < nb) {
                    #pragma unroll
                    for (int nn = 0; nn < 2; ++nn) {
                        acc[m][nn] = __builtin_amdgcn_mfma_f32_16x16x32_bf16(Ah[m], Bh[nn], acc[m][nn], 0, 0, 0);
                        acc[m][nn] = __builtin_amdgcn_mfma_f32_16x16x32_bf16(Al[m], Bh[nn], acc[m][nn], 0, 0, 0);
                    }
                }
            }
        }
        // --- epilogue: D row=(lane>>4)*4+r (box), col=lane&15 (s)
        const float rs = 0.08838834764831845f;  // 1/sqrt(128)
        #pragma unroll
        for (int m = 0; m < 6; ++m)
            #pragma unroll
            for (int r = 0; r < 4; ++r) {
                int b_l = m * 16 + ((lane >> 4) << 2) + r;
                if (b_l < nb) {
                    int bg = start + bp + b_l;
                    float qb = qbias[bg];
                    #pragma unroll
                    for (int nn = 0; nn < 2; ++nn) {
                        int s = sch + (w * 2 + nn) * 16 + (lane & 15);
                        scores[(size_t)bg * S_TOT + s] = (acc[m][nn][r] + qb) * rs;
                    }
                }
            }
        __syncthreads();  // protect LDS before next bp pass
    }
}

// ---------------------------------------------------------------------------
// K3: per-box softmax stats (row max, 1/sum-exp) over S_TOT
// ---------------------------------------------------------------------------
__global__ __launch_bounds__(256) void k3_stats(const float* __restrict__ scores,
                                                float* __restrict__ rmax,
                                                float* __restrict__ rsum) {
    int b = blockIdx.x;
    const float4* row = (const float4*)(scores + (size_t)b * S_TOT);
    __shared__ float red[256];
    float mx = -1e30f;
    for (int i = threadIdx.x; i < S_TOT / 4; i += 256) {
        float4 v = row[i];
        mx = fmaxf(mx, fmaxf(fmaxf(v.x, v.y), fmaxf(v.z, v.w)));
    }
    red[threadIdx.x] = mx;
    __syncthreads();
    for (int st = 128; st > 0; st >>= 1) {
        if (threadIdx.x < st) red[threadIdx.x] = fmaxf(red[threadIdx.x], red[threadIdx.x + st]);
        __syncthreads();
    }
    mx = red[0];
    __syncthreads();
    float sm = 0.f;
    for (int i = threadIdx.x; i < S_TOT / 4; i += 256) {
        float4 v = row[i];
        sm += __expf(v.x - mx) + __expf(v.y - mx) + __expf(v.z - mx) + __expf(v.w - mx);
    }
    red[threadIdx.x] = sm;
    __syncthreads();
    for (int st = 128; st > 0; st >>= 1) {
        if (threadIdx.x < st) red[threadIdx.x] += red[threadIdx.x + st];
        __syncthreads();
    }
    if (threadIdx.x == 0) { rmax[b] = mx; rsum[b] = 1.0f / red[0]; }
}

// ---------------------------------------------------------------------------
// K4: coeff = softmax(scores); attn = 255*coeff (in-place); cctx += coeff.ctx
// via bf16 MFMA.  D row(m)=box, col(n)=channel.  A = p[b][s] (LDS, swizzled),
// B = ctx[c][s] natural layout (LDS, swizzled).  ctx read ONCE per clip.
// Wave (mh,ns) covers m-tiles {mh, mh+2, mh+4} -> active tiles balance
// across waves when nb<=64 (2 tiles each, not 3/1). f32 atomics to cctx.
// ---------------------------------------------------------------------------
__global__ __launch_bounds__(256) void k4_pv(
    const float* __restrict__ ctx, const int* __restrict__ ranges,
    const float* __restrict__ rmax, const float* __restrict__ rsum,
    float* __restrict__ attn, float* __restrict__ cctx)
{
    int n = blockIdx.y;
    int start = ranges[n], Mb = ranges[NCLIP + n] - start;
    if (Mb <= 0) return;
    const float* ctxn = ctx + (size_t)n * DIM_CTX * S_TOT;
    int sch = blockIdx.x * 256;
    int t = threadIdx.x, lane = t & 63, w = t >> 6;
    int mh = w >> 1, ns = w & 1;

    __shared__ unsigned short ls_p[MAXB * 256];   // 49152 B  [96 b][256 s] swz
    __shared__ unsigned short ls_c[32 * 256];     // 16384 B  [32 c][256 s] swz

    for (int bp = 0; bp < Mb; bp += MAXB) {
        int nb = min(MAXB, Mb - bp);
        bool a0v = (mh + 0) * 16 < nb;
        bool a1v = (mh + 2) * 16 < nb;
        bool a2v = (mh + 4) * 16 < nb;
        __syncthreads();
        // stage p (bf16, swizzled); write attn = 255*p (fp32, exact)
        for (int idx = t; idx < MAXB * 64; idx += 256) {
            int b_l = idx >> 6, s4 = (idx & 63) * 4;
            uint2 pk; pk.x = 0u; pk.y = 0u;
            if (b_l < nb) {
                int bg = start + bp + b_l;
                size_t off = (size_t)bg * S_TOT + sch + s4;
                float4 v = *(const float4*)(attn + off);
                float m = rmax[bg], r = rsum[bg];
                float4 p;
                p.x = __expf(v.x - m) * r; p.y = __expf(v.y - m) * r;
                p.z = __expf(v.z - m) * r; p.w = __expf(v.w - m) * r;
                float4 o;
                o.x = 255.f * p.x; o.y = 255.f * p.y; o.z = 255.f * p.z; o.w = 255.f * p.w;
                *(float4*)(attn + off) = o;
                pk.x = f2bf(p.x) | ((unsigned)f2bf(p.y) << 16);
                pk.y = f2bf(p.z) | ((unsigned)f2bf(p.w) << 16);
            }
            int off8 = (b_l * 512 + s4 * 2) ^ ((b_l & 7) << 4);
            *(uint2*)((char*)ls_p + off8) = pk;
        }
        __syncthreads();
        // cache A-frags (p): wave's active m-tiles x 8 k-steps
        short8_t A[3][8];
        int hi16 = (lane >> 4) * 16;
        #pragma unroll
        for (int mi = 0; mi < 3; ++mi) {
            int tm = mh + 2 * mi;
            if (tm * 16 < nb) {
                int row = tm * 16 + (lane & 15);
                int sw = (row & 7) << 4;
                #pragma unroll
                for (int k = 0; k < 8; ++k) {
                    int off = (row * 512 + k * 64 + hi16) ^ sw;
                    A[mi][k] = *(const short8_t*)((const char*)ls_p + off);
                }
            }
        }
        // c-tile loop: stage ctx [32 c][256 s] bf16, 8 MFMA k-steps
        for (int ct = 0; ct < 16; ++ct) {
            __syncthreads();
            for (int idx = t; idx < 32 * 64; idx += 256) {
                int c_l = idx >> 6, s4 = (idx & 63) * 4;
                float4 v = *(const float4*)(ctxn + (size_t)(ct * 32 + c_l) * S_TOT + sch + s4);
                uint2 pk;
                pk.x = f2bf(v.x) | ((unsigned)f2bf(v.y) << 16);
                pk.y = f2bf(v.z) | ((unsigned)f2bf(v.w) << 16);
                int off8 = (c_l * 512 + s4 * 2) ^ ((c_l & 7) << 4);
                *(uint2*)((char*)ls_c + off8) = pk;
            }
            __syncthreads();
            f32x4 acc0 = (f32x4){0,0,0,0}, acc1 = (f32x4){0,0,0,0}, acc2 = (f32x4){0,0,0,0};
            int crow = ns * 16 + (lane & 15);
            int swc = (crow & 7) << 4;
            #pragma unroll
            for (int k = 0; k < 8; ++k) {
                int off = (crow * 512 + k * 64 + hi16) ^ swc;
                short8_t B = *(const short8_t*)((const char*)ls_c + off);
                if (a0v) acc0 = __builtin_amdgcn_mfma_f32_16x16x32_bf16(A[0][k], B, acc0, 0, 0, 0);
                if (a1v) acc1 = __builtin_amdgcn_mfma_f32_16x16x32_bf16(A[1][k], B, acc1, 0, 0, 0);
                if (a2v) acc2 = __builtin_amdgcn_mfma_f32_16x16x32_bf16(A[2][k], B, acc2, 0, 0, 0);
            }
            int cg = ct * 32 + ns * 16 + (lane & 15);
            #pragma unroll
            for (int r = 0; r < 4; ++r) {
                int br = ((lane >> 4) << 2) + r;
                int b0l = (mh + 0) * 16 + br;
                int b1l = (mh + 2) * 16 + br;
                int b2l = (mh + 4) * 16 + br;
                if (a0v && b0l < nb) atomicAdd(&cctx[(size_t)(start + bp + b0l) * DIM_CTX + cg], acc0[r]);
                if (a1v && b1l < nb) atomicAdd(&cctx[(size_t)(start + bp + b1l) * DIM_CTX + cg], acc1[r]);
                if (a2v && b2l < nb) atomicAdd(&cctx[(size_t)(start + bp + b2l) * DIM_CTX + cg], acc2[r]);
            }
        }
    }
}

// ---------------------------------------------------------------------------
// K5: ctx_out[b,v] = cctx[b,:] . W_vals[v,:] + b_vals[v]
// ---------------------------------------------------------------------------
__global__ __launch_bounds__(128) void k5_out(const float* __restrict__ cctx,
                                              const float* __restrict__ W_vals,
                                              const float* __restrict__ b_vals,
                                              float* __restrict__ out) {
    __shared__ float s_c[4 * DIM_CTX];
    int b0 = blockIdx.x * 4;
    const float4* src = (const float4*)(cctx + (size_t)b0 * DIM_CTX);
    for (int i = threadIdx.x; i < 4 * DIM_CTX / 4; i += blockDim.x)
        ((float4*)s_c)[i] = src[i];
    __syncthreads();
    int v = threadIdx.x;
    const float4* wrow = (const float4*)(W_vals + (size_t)v * DIM_CTX);
    float a0 = 0.f, a1 = 0.f, a2 = 0.f, a3 = 0.f;
    for (int i = 0; i < DIM_CTX / 4; ++i) {
        float4 w  = wrow[i];
        float4 c0v = *(const float4*)&s_c[0 * DIM_CTX + i * 4];
        float4 c1v = *(const float4*)&s_c[1 * DIM_CTX + i * 4];
        float4 c2v = *(const float4*)&s_c[2 * DIM_CTX + i * 4];
        float4 c3v = *(const float4*)&s_c[3 * DIM_CTX + i * 4];
        a0 += w.x * c0v.x; a0 += w.y * c0v.y; a0 += w.z * c0v.z; a0 += w.w * c0v.w;
        a1 += w.x * c1v.x; a1 += w.y * c1v.y; a1 += w.z * c1v.z; a1 += w.w * c1v.w;
        a2 += w.x * c2v.x; a2 += w.y * c2v.y; a2 += w.z * c2v.z; a2 += w.w * c2v.w;
        a3 += w.x * c3v.x; a3 += w.y * c3v.y; a3 += w.z * c3v.z; a3 += w.w * c3v.w;
    }
    float bb = b_vals[v];
    out[(size_t)(b0 + 0) * DIM_VAL + v] = a0 + bb;
    out[(size_t)(b0 + 1) * DIM_VAL + v] = a1 + bb;
    out[(size_t)(b0 + 2) * DIM_VAL + v] = a2 + bb;
    out[(size_t)(b0 + 3) * DIM_VAL + v] = a3 + bb;
}

extern "C" void kernel_launch(void* const* d_in, const int* in_sizes, int n_in,
                              void* d_out, int out_size, void* d_ws, size_t ws_size,
                              hipStream_t stream) {
    const float* rois      = (const float*)d_in[0];
    const float* context   = (const float*)d_in[1];
    const int*   batch_idx = (const int*)  d_in[2];
    const float* W_proj    = (const float*)d_in[3];
    const float* b_proj    = (const float*)d_in[4];
    const float* W_keys    = (const float*)d_in[5];
    const float* b_keys    = (const float*)d_in[6];
    const float* W_vals    = (const float*)d_in[7];
    const float* b_vals    = (const float*)d_in[8];

    float* out  = (float*)d_out;                 // [NBOX, DIM_VAL]
    float* attn = out + NBOX * DIM_VAL;          // [NBOX, S_TOT] scores/attn

    // workspace layout (~2.36 MB)
    char* wsb = (char*)d_ws;
    int*   ranges = (int*)wsb;                                   // 64 B (+pad)
    float* q      = (float*)(wsb + 128);                         // 512*128
    float* qbias  = q + NBOX * DIM_KEY;                          // 512
    float* rmaxp  = qbias + NBOX;                                // 512
    float* rsump  = rmaxp + NBOX;                                // 512
    float* cctx   = rsump + NBOX;                                // 512*512
    unsigned short* qW_hi = (unsigned short*)(cctx + NBOX * DIM_CTX);  // 512*512
    unsigned short* qW_lo = qW_hi + NBOX * DIM_CTX;                    // 512*512

    k0_init  <<<dim3(64),       dim3(256), 0, stream>>>(batch_idx, ranges, cctx);
    k1a_q    <<<dim3(NBOX / 4), dim3(128), 0, stream>>>(rois, W_proj, b_proj, q);
    k1b_qw   <<<dim3(NBOX / 4), dim3(256), 0, stream>>>(q, W_keys, b_keys, qW_hi, qW_lo, qbias);
    k2_scores<<<dim3(128, 8),   dim3(256), 0, stream>>>(context, qW_hi, qW_lo, qbias, ranges, attn);
    k3_stats <<<dim3(NBOX),     dim3(256), 0, stream>>>(attn, rmaxp, rsump);
    k4_pv    <<<dim3(64, 8),    dim3(256), 0, stream>>>(context, ranges, rmaxp, rsump, attn, cctx);
    k5_out   <<<dim3(NBOX / 4), dim3(128), 0, stream>>>(cctx, W_vals, b_vals, out);
}